// Round 1
// baseline (6585.185 us; speedup 1.0000x reference)
//
#include <hip/hip_runtime.h>
#include <math.h>

#define N_ 512
#define B_ 128
#define EPSV 1e-20f
#define ITERS 150

// ---------------- Kernel 1: build P0 = softmax(logits + 0.015*g1) ----------------
// One 256-thread block per row; each thread owns cols t and t+256.
__global__ __launch_bounds__(256) void setup_kernel(
    const float* __restrict__ logits,
    const float* __restrict__ u1,
    const int* __restrict__ steps_p,
    float* __restrict__ P0)
{
    const int row = blockIdx.x;                  // 0..B*N-1
    const int t = threadIdx.x;                   // 0..255
    const int lane = t & 63;
    const int wv = t >> 6;                       // 0..3
    const size_t base = (size_t)row * N_;

    const float inv_tau = 1.0f / fmaxf(powf(0.9999f, (float)(*steps_p)), 0.1f);

    const float L0 = logits[base + t];
    const float L1 = logits[base + t + 256];
    const float U0 = u1[base + t];
    const float U1 = u1[base + t + 256];

    const float g0 = -logf(-logf(U0 + 1e-20f) + 1e-20f);
    const float g1 = -logf(-logf(U1 + 1e-20f) + 1e-20f);

    float x0 = (L0 + g0) * inv_tau;
    float x1 = (L1 + g1) * inv_tau;

    __shared__ float red[4];

    // ---- softmax #1: max ----
    float m = fmaxf(x0, x1);
    #pragma unroll
    for (int off = 32; off; off >>= 1) m = fmaxf(m, __shfl_xor(m, off));
    if (lane == 0) red[wv] = m;
    __syncthreads();
    m = fmaxf(fmaxf(red[0], red[1]), fmaxf(red[2], red[3]));
    __syncthreads();

    float e0 = expf(x0 - m), e1 = expf(x1 - m);
    float s = e0 + e1;
    #pragma unroll
    for (int off = 32; off; off >>= 1) s += __shfl_xor(s, off);
    if (lane == 0) red[wv] = s;
    __syncthreads();
    const float Z1 = red[0] + red[1] + red[2] + red[3];
    __syncthreads();

    const float s0 = e0 / Z1, s1 = e1 / Z1;

    float y0 = L0 + 0.015f * s0;
    float y1 = L1 + 0.015f * s1;

    // ---- softmax #2: max ----
    float m2 = fmaxf(y0, y1);
    #pragma unroll
    for (int off = 32; off; off >>= 1) m2 = fmaxf(m2, __shfl_xor(m2, off));
    if (lane == 0) red[wv] = m2;
    __syncthreads();
    m2 = fmaxf(fmaxf(red[0], red[1]), fmaxf(red[2], red[3]));
    __syncthreads();

    float f0 = expf(y0 - m2), f1 = expf(y1 - m2);
    float z = f0 + f1;
    #pragma unroll
    for (int off = 32; off; off >>= 1) z += __shfl_xor(z, off);
    if (lane == 0) red[wv] = z;
    __syncthreads();
    const float Z2 = red[0] + red[1] + red[2] + red[3];

    P0[base + t] = f0 / Z2;
    P0[base + t + 256] = f1 / Z2;
}

// ---------------- Kernel 2: 150 factored Sinkhorn iterations ----------------
// One 1024-thread block per matrix. u,v in LDS. P0 read-only until the final
// fused scale+clip write (in place).
__global__ __launch_bounds__(1024) void sinkhorn_kernel(float* __restrict__ P)
{
    const int b = blockIdx.x;
    float* __restrict__ M = P + (size_t)b * N_ * N_;
    float4* __restrict__ M4 = (float4*)M;

    const int tid = threadIdx.x;
    const int lane = tid & 63;
    const int wave = tid >> 6;      // 0..15
    const int jb = tid & 127;       // float4 column block for v-pass
    const int rq = tid >> 7;        // 0..7

    __shared__ float4 u4s[N_ / 4];
    __shared__ float4 v4s[N_ / 4];
    __shared__ float4 cpart[1024];
    float* u = (float*)u4s;
    float* v = (float*)v4s;

    if (tid < N_) { u[tid] = 1.0f; v[tid] = 1.0f; }
    __syncthreads();

    for (int it = 0; it < ITERS; ++it) {
        // ---- u update: dot_i = sum_j M[i][j] * v[j]; wave w owns rows w, w+16, ...
        for (int r = wave; r < N_; r += 16) {
            const float4* row4 = M4 + (size_t)r * (N_ / 4);
            float4 a = row4[lane];
            float4 bq = row4[lane + 64];
            float4 va = v4s[lane];
            float4 vb = v4s[lane + 64];
            float acc = a.x * va.x + a.y * va.y + a.z * va.z + a.w * va.w
                      + bq.x * vb.x + bq.y * vb.y + bq.z * vb.z + bq.w * vb.w;
            #pragma unroll
            for (int off = 32; off; off >>= 1) acc += __shfl_xor(acc, off);
            if (lane == 0) {
                float uo = u[r];
                float rsum = uo * acc;                 // faithful row>EPS guard
                u[r] = (rsum > EPSV) ? (1.0f / acc) : uo;
            }
        }
        __syncthreads();

        // ---- v update: c_j = sum_i M[i][j] * u[i]; thread owns col-block jb, rows rq+8k
        float4 acc4 = make_float4(0.f, 0.f, 0.f, 0.f);
        for (int r = rq; r < N_; r += 8) {
            float4 mrow = M4[(size_t)r * (N_ / 4) + jb];
            float ur = u[r];
            acc4.x += mrow.x * ur;
            acc4.y += mrow.y * ur;
            acc4.z += mrow.z * ur;
            acc4.w += mrow.w * ur;
        }
        cpart[tid] = acc4;
        __syncthreads();
        if (tid < 128) {
            float4 cs = cpart[tid];
            #pragma unroll
            for (int k = 1; k < 8; ++k) {
                float4 p = cpart[tid + (k << 7)];
                cs.x += p.x; cs.y += p.y; cs.z += p.z; cs.w += p.w;
            }
            float vo0 = v[4 * tid + 0], vo1 = v[4 * tid + 1];
            float vo2 = v[4 * tid + 2], vo3 = v[4 * tid + 3];
            v[4 * tid + 0] = (vo0 * cs.x > EPSV) ? (1.0f / cs.x) : vo0;
            v[4 * tid + 1] = (vo1 * cs.y > EPSV) ? (1.0f / cs.y) : vo1;
            v[4 * tid + 2] = (vo2 * cs.z > EPSV) ? (1.0f / cs.z) : vo2;
            v[4 * tid + 3] = (vo3 * cs.w > EPSV) ? (1.0f / cs.w) : vo3;
        }
        __syncthreads();
    }

    // ---- final: P = clip(P0 * u_i * v_j, EPS, 1.0), in place ----
    for (int r = rq; r < N_; r += 8) {
        size_t idx = (size_t)r * (N_ / 4) + jb;
        float4 mrow = M4[idx];
        float ur = u[r];
        float4 vv = v4s[jb];
        mrow.x = fminf(fmaxf(mrow.x * ur * vv.x, EPSV), 1.0f);
        mrow.y = fminf(fmaxf(mrow.y * ur * vv.y, EPSV), 1.0f);
        mrow.z = fminf(fmaxf(mrow.z * ur * vv.z, EPSV), 1.0f);
        mrow.w = fminf(fmaxf(mrow.w * ur * vv.w, EPSV), 1.0f);
        M4[idx] = mrow;
    }
}

extern "C" void kernel_launch(void* const* d_in, const int* in_sizes, int n_in,
                              void* d_out, int out_size, void* d_ws, size_t ws_size,
                              hipStream_t stream) {
    const float* logits = (const float*)d_in[0];
    const float* u1     = (const float*)d_in[1];
    // d_in[2] (u2) is dead in the forward value: st - stop_gradient(st) == 0.
    const int* steps    = (const int*)d_in[3];
    float* out = (float*)d_out;

    // Kernel 1: P0 into d_out (one block per row)
    setup_kernel<<<B_ * N_, 256, 0, stream>>>(logits, u1, steps, out);

    // Kernel 2: 150 factored Sinkhorn iterations + fused final scale/clip
    sinkhorn_kernel<<<B_, 1024, 0, stream>>>(out);
}

// Round 2
// 259.256 us; speedup vs baseline: 25.4003x; 25.4003x over previous
//
#include <hip/hip_runtime.h>
#include <math.h>

#define N_ 512
#define B_ 128
#define EPSV 1e-20f
#define ITERS 150
#define CONV_TOL 1e-5f

typedef __attribute__((ext_vector_type(8))) unsigned short ushort8;

static __device__ __forceinline__ float bf2f(unsigned short h) {
    union { unsigned int u; float f; } c; c.u = ((unsigned int)h) << 16; return c.f;
}
static __device__ __forceinline__ unsigned short f2bf(float f) {
    union { float f; unsigned int u; } c; c.f = f;
    unsigned int r = (c.u + 0x7FFFu + ((c.u >> 16) & 1u)) >> 16;
    return (unsigned short)r;
}

// ---------------- Kernel 1: P0 = softmax(logits + 0.015*softmax((logits+g1)/tau)) ----
// One 256-thread block per row; thread owns cols t and t+256.
// BF16_OUT: write bf16 into ws; else fp32 into out.
template <bool BF16_OUT>
__global__ __launch_bounds__(256) void setup_kernel(
    const float* __restrict__ logits,
    const float* __restrict__ u1,
    const int* __restrict__ steps_p,
    float* __restrict__ P0f,
    unsigned short* __restrict__ P0h)
{
    const int row = blockIdx.x;
    const int t = threadIdx.x;
    const int lane = t & 63;
    const int wv = t >> 6;
    const size_t base = (size_t)row * N_;

    const float inv_tau = 1.0f / fmaxf(powf(0.9999f, (float)(*steps_p)), 0.1f);

    const float L0 = logits[base + t];
    const float L1 = logits[base + t + 256];
    const float U0 = u1[base + t];
    const float U1 = u1[base + t + 256];

    const float g0 = -logf(-logf(U0 + 1e-20f) + 1e-20f);
    const float g1 = -logf(-logf(U1 + 1e-20f) + 1e-20f);

    float x0 = (L0 + g0) * inv_tau;
    float x1 = (L1 + g1) * inv_tau;

    __shared__ float red[4];

    float m = fmaxf(x0, x1);
    #pragma unroll
    for (int off = 32; off; off >>= 1) m = fmaxf(m, __shfl_xor(m, off));
    if (lane == 0) red[wv] = m;
    __syncthreads();
    m = fmaxf(fmaxf(red[0], red[1]), fmaxf(red[2], red[3]));
    __syncthreads();

    float e0 = expf(x0 - m), e1 = expf(x1 - m);
    float s = e0 + e1;
    #pragma unroll
    for (int off = 32; off; off >>= 1) s += __shfl_xor(s, off);
    if (lane == 0) red[wv] = s;
    __syncthreads();
    const float Z1 = red[0] + red[1] + red[2] + red[3];
    __syncthreads();

    float y0 = L0 + 0.015f * (e0 / Z1);
    float y1 = L1 + 0.015f * (e1 / Z1);

    float m2 = fmaxf(y0, y1);
    #pragma unroll
    for (int off = 32; off; off >>= 1) m2 = fmaxf(m2, __shfl_xor(m2, off));
    if (lane == 0) red[wv] = m2;
    __syncthreads();
    m2 = fmaxf(fmaxf(red[0], red[1]), fmaxf(red[2], red[3]));
    __syncthreads();

    float f0 = expf(y0 - m2), f1 = expf(y1 - m2);
    float z = f0 + f1;
    #pragma unroll
    for (int off = 32; off; off >>= 1) z += __shfl_xor(z, off);
    if (lane == 0) red[wv] = z;
    __syncthreads();
    const float Z2 = red[0] + red[1] + red[2] + red[3];

    if (BF16_OUT) {
        P0h[base + t]       = f2bf(f0 / Z2);
        P0h[base + t + 256] = f2bf(f1 / Z2);
    } else {
        P0f[base + t]       = f0 / Z2;
        P0f[base + t + 256] = f1 / Z2;
    }
}

// ---------------- Kernel 2 (main path): single-sweep factored Sinkhorn over bf16 P0 --
// One 1024-thread block (16 waves) per matrix. Wave w owns rows [32w, 32w+32).
// Per iteration: ONE matrix read; row dot -> u update; column partials
// accumulated in registers with the NEW u; 16-way LDS reduce -> v update;
// early-exit when max|dv/v| < CONV_TOL.
__global__ __launch_bounds__(1024) void sinkhorn_bf16(
    const unsigned short* __restrict__ Pb, float* __restrict__ Out)
{
    const int b = blockIdx.x;
    const unsigned short* __restrict__ M = Pb + (size_t)b * N_ * N_;
    float* __restrict__ O = Out + (size_t)b * N_ * N_;

    const int tid = threadIdx.x;
    const int lane = tid & 63;
    const int wave = tid >> 6;        // 0..15
    const int c0 = lane << 3;         // this lane's 8 columns
    const int rbase = wave << 5;      // 32 rows per wave

    __shared__ float u_s[N_];
    __shared__ float v_s[N_];
    __shared__ float cpart[16][N_];   // 32 KB column partials
    __shared__ float wmax[8];

    if (tid < N_) { u_s[tid] = 1.0f; v_s[tid] = 1.0f; }
    __syncthreads();

    for (int it = 0; it < ITERS; ++it) {
        float vr[8];
        #pragma unroll
        for (int k = 0; k < 8; ++k) vr[k] = v_s[c0 + k];
        float colacc[8] = {0.f,0.f,0.f,0.f,0.f,0.f,0.f,0.f};

        #pragma unroll 4
        for (int rr = 0; rr < 32; ++rr) {
            const int r = rbase + rr;
            ushort8 h = *(const ushort8*)(M + ((size_t)r << 9) + c0);
            float x[8];
            #pragma unroll
            for (int k = 0; k < 8; ++k) x[k] = bf2f(h[k]);
            float d = x[0]*vr[0] + x[1]*vr[1] + x[2]*vr[2] + x[3]*vr[3]
                    + x[4]*vr[4] + x[5]*vr[5] + x[6]*vr[6] + x[7]*vr[7];
            #pragma unroll
            for (int off = 32; off; off >>= 1) d += __shfl_xor(d, off);
            const float uo = u_s[r];
            const float un = (uo * d > EPSV) ? (1.0f / d) : uo;  // faithful row>EPS guard
            if (lane == 0) u_s[r] = un;
            #pragma unroll
            for (int k = 0; k < 8; ++k) colacc[k] += x[k] * un;
        }
        #pragma unroll
        for (int k = 0; k < 8; ++k) cpart[wave][c0 + k] = colacc[k];
        __syncthreads();                       // (A) cpart + u_s ready

        float mrel = 0.0f;
        if (tid < N_) {
            float c = 0.0f;
            #pragma unroll
            for (int w = 0; w < 16; ++w) c += cpart[w][tid];
            const float vo = v_s[tid];
            const float vn = (vo * c > EPSV) ? (1.0f / c) : vo;  // faithful col>EPS guard
            v_s[tid] = vn;
            mrel = fabsf(vn - vo) / vo;        // vo > 0 always
        }
        #pragma unroll
        for (int off = 32; off; off >>= 1) mrel = fmaxf(mrel, __shfl_xor(mrel, off));
        if (lane == 0 && wave < 8) wmax[wave] = mrel;
        __syncthreads();                       // (B) v_s + wmax ready

        float mx = wmax[0];
        #pragma unroll
        for (int w = 1; w < 8; ++w) mx = fmaxf(mx, wmax[w]);
        if (mx < CONV_TOL) break;              // uniform across block; deterministic
    }

    // ---- final: Out = clip(P0 * u_i * v_j, EPS, 1.0) ----
    float vrf[8];
    #pragma unroll
    for (int k = 0; k < 8; ++k) vrf[k] = v_s[c0 + k];
    for (int rr = 0; rr < 32; ++rr) {
        const int r = rbase + rr;
        ushort8 h = *(const ushort8*)(M + ((size_t)r << 9) + c0);
        const float ur = u_s[r];
        float o[8];
        #pragma unroll
        for (int k = 0; k < 8; ++k)
            o[k] = fminf(fmaxf(bf2f(h[k]) * ur * vrf[k], EPSV), 1.0f);
        float4* dst = (float4*)(O + ((size_t)r << 9) + c0);
        dst[0] = make_float4(o[0], o[1], o[2], o[3]);
        dst[1] = make_float4(o[4], o[5], o[6], o[7]);
    }
}

// ---------------- Fallback (ws too small): round-1 fp32 in-place kernel ------------
__global__ __launch_bounds__(1024) void sinkhorn_f32(float* __restrict__ P)
{
    const int b = blockIdx.x;
    float* __restrict__ M = P + (size_t)b * N_ * N_;
    float4* __restrict__ M4 = (float4*)M;

    const int tid = threadIdx.x;
    const int lane = tid & 63;
    const int wave = tid >> 6;
    const int jb = tid & 127;
    const int rq = tid >> 7;

    __shared__ float4 u4s[N_ / 4];
    __shared__ float4 v4s[N_ / 4];
    __shared__ float4 cpartf[1024];
    float* u = (float*)u4s;
    float* v = (float*)v4s;

    if (tid < N_) { u[tid] = 1.0f; v[tid] = 1.0f; }
    __syncthreads();

    for (int it = 0; it < ITERS; ++it) {
        for (int r = wave; r < N_; r += 16) {
            const float4* row4 = M4 + (size_t)r * (N_ / 4);
            float4 a = row4[lane];
            float4 bq = row4[lane + 64];
            float4 va = v4s[lane];
            float4 vb = v4s[lane + 64];
            float acc = a.x*va.x + a.y*va.y + a.z*va.z + a.w*va.w
                      + bq.x*vb.x + bq.y*vb.y + bq.z*vb.z + bq.w*vb.w;
            #pragma unroll
            for (int off = 32; off; off >>= 1) acc += __shfl_xor(acc, off);
            if (lane == 0) {
                float uo = u[r];
                u[r] = (uo * acc > EPSV) ? (1.0f / acc) : uo;
            }
        }
        __syncthreads();

        float4 acc4 = make_float4(0.f, 0.f, 0.f, 0.f);
        for (int r = rq; r < N_; r += 8) {
            float4 mrow = M4[(size_t)r * (N_ / 4) + jb];
            float ur = u[r];
            acc4.x += mrow.x * ur; acc4.y += mrow.y * ur;
            acc4.z += mrow.z * ur; acc4.w += mrow.w * ur;
        }
        cpartf[tid] = acc4;
        __syncthreads();
        if (tid < 128) {
            float4 cs = cpartf[tid];
            #pragma unroll
            for (int k = 1; k < 8; ++k) {
                float4 p = cpartf[tid + (k << 7)];
                cs.x += p.x; cs.y += p.y; cs.z += p.z; cs.w += p.w;
            }
            float vo0 = v[4*tid+0], vo1 = v[4*tid+1], vo2 = v[4*tid+2], vo3 = v[4*tid+3];
            v[4*tid+0] = (vo0 * cs.x > EPSV) ? (1.0f / cs.x) : vo0;
            v[4*tid+1] = (vo1 * cs.y > EPSV) ? (1.0f / cs.y) : vo1;
            v[4*tid+2] = (vo2 * cs.z > EPSV) ? (1.0f / cs.z) : vo2;
            v[4*tid+3] = (vo3 * cs.w > EPSV) ? (1.0f / cs.w) : vo3;
        }
        __syncthreads();
    }

    for (int r = rq; r < N_; r += 8) {
        size_t idx = (size_t)r * (N_ / 4) + jb;
        float4 mrow = M4[idx];
        float ur = u[r];
        float4 vv = v4s[jb];
        mrow.x = fminf(fmaxf(mrow.x * ur * vv.x, EPSV), 1.0f);
        mrow.y = fminf(fmaxf(mrow.y * ur * vv.y, EPSV), 1.0f);
        mrow.z = fminf(fmaxf(mrow.z * ur * vv.z, EPSV), 1.0f);
        mrow.w = fminf(fmaxf(mrow.w * ur * vv.w, EPSV), 1.0f);
        M4[idx] = mrow;
    }
}

extern "C" void kernel_launch(void* const* d_in, const int* in_sizes, int n_in,
                              void* d_out, int out_size, void* d_ws, size_t ws_size,
                              hipStream_t stream) {
    const float* logits = (const float*)d_in[0];
    const float* u1     = (const float*)d_in[1];
    // d_in[2] (u2) is dead in the forward value: st - stop_gradient(st) == 0.
    const int* steps    = (const int*)d_in[3];
    float* out = (float*)d_out;

    const size_t need = (size_t)B_ * N_ * N_ * sizeof(unsigned short); // 64 MB

    if (ws_size >= need) {
        unsigned short* P0h = (unsigned short*)d_ws;
        setup_kernel<true><<<B_ * N_, 256, 0, stream>>>(logits, u1, steps, nullptr, P0h);
        sinkhorn_bf16<<<B_, 1024, 0, stream>>>(P0h, out);
    } else {
        setup_kernel<false><<<B_ * N_, 256, 0, stream>>>(logits, u1, steps, out, nullptr);
        sinkhorn_f32<<<B_, 1024, 0, stream>>>(out);
    }
}

// Round 3
// 183.544 us; speedup vs baseline: 35.8780x; 1.4125x over previous
//
#include <hip/hip_runtime.h>
#include <math.h>

#define N_ 512
#define B_ 128
#define EPSV 1e-20f
#define ITERS 150
#define CONV_TOL 1e-5f

typedef __attribute__((ext_vector_type(8))) unsigned short ushort8;

static __device__ __forceinline__ float bf2f(unsigned short h) {
    union { unsigned int u; float f; } c; c.u = ((unsigned int)h) << 16; return c.f;
}
static __device__ __forceinline__ unsigned short f2bf(float f) {
    union { float f; unsigned int u; } c; c.f = f;
    unsigned int r = (c.u + 0x7FFFu + ((c.u >> 16) & 1u)) >> 16;
    return (unsigned short)r;
}
static __device__ __forceinline__ float frcp(float x) {
    return __builtin_amdgcn_rcpf(x);
}

// ---------------- Kernel 1: P0 = softmax(logits + 0.015*softmax((logits+g1)/tau)) ----
// Wave-per-row, sync-free: 4 waves/block, wave owns one row, lane owns 8 contiguous
// cols. Fast HW transcendentals (__expf/__logf/v_rcp) — error ~1e-6 rel, invisible
// under bf16 output quantization.
template <bool BF16_OUT>
__global__ __launch_bounds__(256) void setup_kernel(
    const float* __restrict__ logits,
    const float* __restrict__ u1,
    const int* __restrict__ steps_p,
    float* __restrict__ P0f,
    unsigned short* __restrict__ P0h)
{
    const int wave = threadIdx.x >> 6;
    const int lane = threadIdx.x & 63;
    const int row  = (blockIdx.x << 2) + wave;
    const size_t base = (size_t)row * N_;

    // tau = max(0.9999^steps, 0.1);  0.9999^s = exp(s * ln 0.9999)
    const float stepsf = (float)(*steps_p);
    const float tau = fmaxf(__expf(stepsf * -1.0000500033e-4f), 0.1f);
    const float inv_tau = frcp(tau);

    const float4* Lp = (const float4*)(logits + base);
    const float4* Up = (const float4*)(u1 + base);
    const float4 l0 = Lp[2 * lane], l1 = Lp[2 * lane + 1];
    const float4 q0 = Up[2 * lane], q1 = Up[2 * lane + 1];
    float L[8] = {l0.x, l0.y, l0.z, l0.w, l1.x, l1.y, l1.z, l1.w};
    float U[8] = {q0.x, q0.y, q0.z, q0.w, q1.x, q1.y, q1.z, q1.w};

    // x = (L + gumbel(U)) / tau
    float x[8];
    #pragma unroll
    for (int k = 0; k < 8; ++k) {
        float g = -__logf(-__logf(U[k] + 1e-20f) + 1e-20f);
        x[k] = (L[k] + g) * inv_tau;
    }

    // softmax #1 over the row
    float m = x[0];
    #pragma unroll
    for (int k = 1; k < 8; ++k) m = fmaxf(m, x[k]);
    #pragma unroll
    for (int off = 32; off; off >>= 1) m = fmaxf(m, __shfl_xor(m, off));

    float e[8], s = 0.0f;
    #pragma unroll
    for (int k = 0; k < 8; ++k) { e[k] = __expf(x[k] - m); s += e[k]; }
    #pragma unroll
    for (int off = 32; off; off >>= 1) s += __shfl_xor(s, off);
    const float rZ1 = frcp(s);

    // y = L + 0.015 * softmax1
    float y[8];
    #pragma unroll
    for (int k = 0; k < 8; ++k) y[k] = L[k] + 0.015f * (e[k] * rZ1);

    // softmax #2 over the row
    float m2 = y[0];
    #pragma unroll
    for (int k = 1; k < 8; ++k) m2 = fmaxf(m2, y[k]);
    #pragma unroll
    for (int off = 32; off; off >>= 1) m2 = fmaxf(m2, __shfl_xor(m2, off));

    float f[8], z = 0.0f;
    #pragma unroll
    for (int k = 0; k < 8; ++k) { f[k] = __expf(y[k] - m2); z += f[k]; }
    #pragma unroll
    for (int off = 32; off; off >>= 1) z += __shfl_xor(z, off);
    const float rZ2 = frcp(z);

    if (BF16_OUT) {
        ushort8 o;
        #pragma unroll
        for (int k = 0; k < 8; ++k) o[k] = f2bf(f[k] * rZ2);
        *(ushort8*)(P0h + base + (lane << 3)) = o;
    } else {
        const int c0 = lane << 3;
        float4* dst = (float4*)(P0f + base + c0);
        dst[0] = make_float4(f[0]*rZ2, f[1]*rZ2, f[2]*rZ2, f[3]*rZ2);
        dst[1] = make_float4(f[4]*rZ2, f[5]*rZ2, f[6]*rZ2, f[7]*rZ2);
    }
}

// ---------------- Kernel 2 (main path): single-sweep factored Sinkhorn over bf16 P0 --
// One 1024-thread block (16 waves) per matrix. Wave w owns rows [32w, 32w+32).
// Per iteration: ONE matrix read; row dot -> u update; column partials
// accumulated in registers with the NEW u; 16-way LDS reduce -> v update;
// early-exit when max|dv/v| < CONV_TOL.
__global__ __launch_bounds__(1024) void sinkhorn_bf16(
    const unsigned short* __restrict__ Pb, float* __restrict__ Out)
{
    const int b = blockIdx.x;
    const unsigned short* __restrict__ M = Pb + (size_t)b * N_ * N_;
    float* __restrict__ O = Out + (size_t)b * N_ * N_;

    const int tid = threadIdx.x;
    const int lane = tid & 63;
    const int wave = tid >> 6;        // 0..15
    const int c0 = lane << 3;         // this lane's 8 columns
    const int rbase = wave << 5;      // 32 rows per wave

    __shared__ float u_s[N_];
    __shared__ float v_s[N_];
    __shared__ float cpart[16][N_];   // 32 KB column partials
    __shared__ float wmax[8];

    if (tid < N_) { u_s[tid] = 1.0f; v_s[tid] = 1.0f; }
    __syncthreads();

    for (int it = 0; it < ITERS; ++it) {
        float vr[8];
        #pragma unroll
        for (int k = 0; k < 8; ++k) vr[k] = v_s[c0 + k];
        float colacc[8] = {0.f,0.f,0.f,0.f,0.f,0.f,0.f,0.f};

        #pragma unroll 4
        for (int rr = 0; rr < 32; ++rr) {
            const int r = rbase + rr;
            ushort8 h = *(const ushort8*)(M + ((size_t)r << 9) + c0);
            float x[8];
            #pragma unroll
            for (int k = 0; k < 8; ++k) x[k] = bf2f(h[k]);
            float d = x[0]*vr[0] + x[1]*vr[1] + x[2]*vr[2] + x[3]*vr[3]
                    + x[4]*vr[4] + x[5]*vr[5] + x[6]*vr[6] + x[7]*vr[7];
            #pragma unroll
            for (int off = 32; off; off >>= 1) d += __shfl_xor(d, off);
            const float uo = u_s[r];
            const float un = (uo * d > EPSV) ? frcp(d) : uo;  // faithful row>EPS guard
            if (lane == 0) u_s[r] = un;
            #pragma unroll
            for (int k = 0; k < 8; ++k) colacc[k] += x[k] * un;
        }
        #pragma unroll
        for (int k = 0; k < 8; ++k) cpart[wave][c0 + k] = colacc[k];
        __syncthreads();                       // (A) cpart + u_s ready

        float mrel = 0.0f;
        if (tid < N_) {
            float c = 0.0f;
            #pragma unroll
            for (int w = 0; w < 16; ++w) c += cpart[w][tid];
            const float vo = v_s[tid];
            const float vn = (vo * c > EPSV) ? frcp(c) : vo;  // faithful col>EPS guard
            v_s[tid] = vn;
            mrel = fabsf(vn - vo) * frcp(vo);  // vo > 0 always
        }
        #pragma unroll
        for (int off = 32; off; off >>= 1) mrel = fmaxf(mrel, __shfl_xor(mrel, off));
        if (lane == 0 && wave < 8) wmax[wave] = mrel;
        __syncthreads();                       // (B) v_s + wmax ready

        float mx = wmax[0];
        #pragma unroll
        for (int w = 1; w < 8; ++w) mx = fmaxf(mx, wmax[w]);
        if (mx < CONV_TOL) break;              // uniform across block; deterministic
    }

    // ---- final: Out = clip(P0 * u_i * v_j, EPS, 1.0) ----
    float vrf[8];
    #pragma unroll
    for (int k = 0; k < 8; ++k) vrf[k] = v_s[c0 + k];
    for (int rr = 0; rr < 32; ++rr) {
        const int r = rbase + rr;
        ushort8 h = *(const ushort8*)(M + ((size_t)r << 9) + c0);
        const float ur = u_s[r];
        float o[8];
        #pragma unroll
        for (int k = 0; k < 8; ++k)
            o[k] = fminf(fmaxf(bf2f(h[k]) * ur * vrf[k], EPSV), 1.0f);
        float4* dst = (float4*)(O + ((size_t)r << 9) + c0);
        dst[0] = make_float4(o[0], o[1], o[2], o[3]);
        dst[1] = make_float4(o[4], o[5], o[6], o[7]);
    }
}

// ---------------- Fallback (ws too small): fp32 in-place kernel ------------
__global__ __launch_bounds__(1024) void sinkhorn_f32(float* __restrict__ P)
{
    const int b = blockIdx.x;
    float* __restrict__ M = P + (size_t)b * N_ * N_;
    float4* __restrict__ M4 = (float4*)M;

    const int tid = threadIdx.x;
    const int lane = tid & 63;
    const int wave = tid >> 6;
    const int jb = tid & 127;
    const int rq = tid >> 7;

    __shared__ float4 u4s[N_ / 4];
    __shared__ float4 v4s[N_ / 4];
    __shared__ float4 cpartf[1024];
    float* u = (float*)u4s;
    float* v = (float*)v4s;

    if (tid < N_) { u[tid] = 1.0f; v[tid] = 1.0f; }
    __syncthreads();

    for (int it = 0; it < ITERS; ++it) {
        for (int r = wave; r < N_; r += 16) {
            const float4* row4 = M4 + (size_t)r * (N_ / 4);
            float4 a = row4[lane];
            float4 bq = row4[lane + 64];
            float4 va = v4s[lane];
            float4 vb = v4s[lane + 64];
            float acc = a.x*va.x + a.y*va.y + a.z*va.z + a.w*va.w
                      + bq.x*vb.x + bq.y*vb.y + bq.z*vb.z + bq.w*vb.w;
            #pragma unroll
            for (int off = 32; off; off >>= 1) acc += __shfl_xor(acc, off);
            if (lane == 0) {
                float uo = u[r];
                u[r] = (uo * acc > EPSV) ? (1.0f / acc) : uo;
            }
        }
        __syncthreads();

        float4 acc4 = make_float4(0.f, 0.f, 0.f, 0.f);
        for (int r = rq; r < N_; r += 8) {
            float4 mrow = M4[(size_t)r * (N_ / 4) + jb];
            float ur = u[r];
            acc4.x += mrow.x * ur; acc4.y += mrow.y * ur;
            acc4.z += mrow.z * ur; acc4.w += mrow.w * ur;
        }
        cpartf[tid] = acc4;
        __syncthreads();
        if (tid < 128) {
            float4 cs = cpartf[tid];
            #pragma unroll
            for (int k = 1; k < 8; ++k) {
                float4 p = cpartf[tid + (k << 7)];
                cs.x += p.x; cs.y += p.y; cs.z += p.z; cs.w += p.w;
            }
            float vo0 = v[4*tid+0], vo1 = v[4*tid+1], vo2 = v[4*tid+2], vo3 = v[4*tid+3];
            v[4*tid+0] = (vo0 * cs.x > EPSV) ? (1.0f / cs.x) : vo0;
            v[4*tid+1] = (vo1 * cs.y > EPSV) ? (1.0f / cs.y) : vo1;
            v[4*tid+2] = (vo2 * cs.z > EPSV) ? (1.0f / cs.z) : vo2;
            v[4*tid+3] = (vo3 * cs.w > EPSV) ? (1.0f / cs.w) : vo3;
        }
        __syncthreads();
    }

    for (int r = rq; r < N_; r += 8) {
        size_t idx = (size_t)r * (N_ / 4) + jb;
        float4 mrow = M4[idx];
        float ur = u[r];
        float4 vv = v4s[jb];
        mrow.x = fminf(fmaxf(mrow.x * ur * vv.x, EPSV), 1.0f);
        mrow.y = fminf(fmaxf(mrow.y * ur * vv.y, EPSV), 1.0f);
        mrow.z = fminf(fmaxf(mrow.z * ur * vv.z, EPSV), 1.0f);
        mrow.w = fminf(fmaxf(mrow.w * ur * vv.w, EPSV), 1.0f);
        M4[idx] = mrow;
    }
}

extern "C" void kernel_launch(void* const* d_in, const int* in_sizes, int n_in,
                              void* d_out, int out_size, void* d_ws, size_t ws_size,
                              hipStream_t stream) {
    const float* logits = (const float*)d_in[0];
    const float* u1     = (const float*)d_in[1];
    // d_in[2] (u2) is dead in the forward value: st - stop_gradient(st) == 0.
    const int* steps    = (const int*)d_in[3];
    float* out = (float*)d_out;

    const size_t need = (size_t)B_ * N_ * N_ * sizeof(unsigned short); // 64 MB

    if (ws_size >= need) {
        unsigned short* P0h = (unsigned short*)d_ws;
        setup_kernel<true><<<B_ * N_ / 4, 256, 0, stream>>>(logits, u1, steps, nullptr, P0h);
        sinkhorn_bf16<<<B_, 1024, 0, stream>>>(P0h, out);
    } else {
        setup_kernel<false><<<B_ * N_ / 4, 256, 0, stream>>>(logits, u1, steps, out, nullptr);
        sinkhorn_f32<<<B_, 1024, 0, stream>>>(out);
    }
}